// Round 2
// baseline (287.661 us; speedup 1.0000x reference)
//
#include <hip/hip_runtime.h>
#include <cstdint>

#define BN 9216      // N = H*W = 96*96
#define NB 2         // batch
#define CIN 64       // C
#define DI 32        // inter

typedef __attribute__((ext_vector_type(4))) float f32x4;
typedef __attribute__((ext_vector_type(8))) __bf16 bf16x8;
typedef __attribute__((ext_vector_type(4))) unsigned int u32x4;

// fp32 -> bf16 bits, round-to-nearest-even (manual, no API-version risk)
__device__ __forceinline__ unsigned short f2bf(float f) {
    unsigned int u = __builtin_bit_cast(unsigned int, f);
    u += 0x7FFFu + ((u >> 16) & 1u);
    return (unsigned short)(u >> 16);
}
__device__ __forceinline__ unsigned int packbf(float lo, float hi) {
    return (unsigned int)f2bf(lo) | ((unsigned int)f2bf(hi) << 16);
}

// ---------------------------------------------------------------------------
// Kernel 1: fused conv1x1 for phi (Q), theta (K), g (V).
//   qT: [B][N][32] bf16   (Q^T layout, rows contiguous -> B-operand of QK^T)
//   kT: [B][N][32] bf16   (K^T layout, rows contiguous -> A-operand of QK^T)
//   v : [B][32][N] bf16   (natural layout -> A-operand of PV)
// ---------------------------------------------------------------------------
__global__ __launch_bounds__(256) void qkv_kernel(
    const float* __restrict__ x,
    const float* __restrict__ g_w, const float* __restrict__ g_b,
    const float* __restrict__ th_w, const float* __restrict__ th_b,
    const float* __restrict__ ph_w, const float* __restrict__ ph_b,
    unsigned short* __restrict__ qT, unsigned short* __restrict__ kT,
    unsigned short* __restrict__ vv)
{
    __shared__ float wsh[DI * CIN];
    __shared__ float bsh[DI];
    const int which = blockIdx.y;  // 0 = phi->qT, 1 = theta->kT, 2 = g->v
    const int b = blockIdx.z;
    const int tid = threadIdx.x;
    const float* w    = (which == 0) ? ph_w : (which == 1) ? th_w : g_w;
    const float* bias = (which == 0) ? ph_b : (which == 1) ? th_b : g_b;
    for (int i = tid; i < DI * CIN; i += 256) wsh[i] = w[i];
    if (tid < DI) bsh[tid] = bias[tid];
    __syncthreads();

    const int n = blockIdx.x * 256 + tid;
    const float* xp = x + (size_t)b * CIN * BN + n;

    float acc[DI];
#pragma unroll
    for (int o = 0; o < DI; ++o) acc[o] = bsh[o];
    for (int c = 0; c < CIN; ++c) {
        float xv = xp[(size_t)c * BN];
#pragma unroll
        for (int o = 0; o < DI; ++o) acc[o] += wsh[o * CIN + c] * xv;
    }

    if (which == 2) {
        unsigned short* vp = vv + (size_t)b * DI * BN + n;
#pragma unroll
        for (int o = 0; o < DI; ++o) vp[(size_t)o * BN] = f2bf(acc[o]);
    } else {
        unsigned short* outp = ((which == 0) ? qT : kT) + ((size_t)b * BN + n) * DI;
        unsigned int pk[16];
#pragma unroll
        for (int j = 0; j < 16; ++j) pk[j] = packbf(acc[2 * j], acc[2 * j + 1]);
        u32x4* o4 = (u32x4*)outp;
#pragma unroll
        for (int j = 0; j < 4; ++j) {
            u32x4 t = {pk[4 * j], pk[4 * j + 1], pk[4 * j + 2], pk[4 * j + 3]};
            o4[j] = t;
        }
    }
}

// ---------------------------------------------------------------------------
// Kernel 2: flash attention. One wave per 16 query rows.
// Swapped QK^T: S^T = mfma(A=K_tile[16m x 32d], B=Q_tile[32d x 16n])
//   -> lane holds col n = lane&15, rows m = 4*(lane>>4) + reg.
// Online softmax over m (2x shfl_xor reduce). P repacked to bf16 and
// lane-shuffled into the PV B-operand layout; PV: yT = mfma(V_tile, P).
// ---------------------------------------------------------------------------
__global__ __launch_bounds__(64) void attn_kernel(
    const unsigned short* __restrict__ qT, const unsigned short* __restrict__ kT,
    const unsigned short* __restrict__ vv, float* __restrict__ yT)
{
    const int b = blockIdx.y;
    const int n0 = blockIdx.x * 16;
    const int lane = threadIdx.x;
    const int h = lane >> 4;      // lane group 0..3
    const int q = lane & 15;      // column (query) index within tile

    const unsigned short* qTb = qT + (size_t)b * BN * DI;
    const unsigned short* kTb = kT + (size_t)b * BN * DI;
    const unsigned short* vb  = vv + (size_t)b * DI * BN;

    // Q fragment (B-operand): B[k=d][n] = phi[d][n0+n]; lane: n=q, d=8h+j
    bf16x8 qfrag = *(const bf16x8*)(qTb + ((size_t)(n0 + q)) * DI + 8 * h);
    f32x4 zero = {0.f, 0.f, 0.f, 0.f};
    f32x4 acc0 = zero, acc1 = zero;    // yT rows i=4h+t and 16+4h+t, col n0+q
    float mrun = -INFINITY, lrun = 0.f;

    const int src0 = q + 16 * ((2 * h) & 3);
    const int src1 = q + 16 * ((2 * h + 1) & 3);

    for (int m0 = 0; m0 < BN; m0 += 32) {
        // K fragments (A-operand): A[m][d] = theta[d][m0+m]; lane: m=q, d=8h+j
        bf16x8 k0 = *(const bf16x8*)(kTb + ((size_t)(m0 + q)) * DI + 8 * h);
        bf16x8 k1 = *(const bf16x8*)(kTb + ((size_t)(m0 + 16 + q)) * DI + 8 * h);
        f32x4 s0 = __builtin_amdgcn_mfma_f32_16x16x32_bf16(k0, qfrag, zero, 0, 0, 0);
        f32x4 s1 = __builtin_amdgcn_mfma_f32_16x16x32_bf16(k1, qfrag, zero, 0, 0, 0);
        // s0[t]: S[m0+4h+t][n0+q]; s1[t]: S[m0+16+4h+t][n0+q]

        float tmax = fmaxf(fmaxf(fmaxf(s0[0], s0[1]), fmaxf(s0[2], s0[3])),
                           fmaxf(fmaxf(s1[0], s1[1]), fmaxf(s1[2], s1[3])));
        tmax = fmaxf(tmax, __shfl_xor(tmax, 16, 64));
        tmax = fmaxf(tmax, __shfl_xor(tmax, 32, 64));
        float mnew = fmaxf(mrun, tmax);
        float corr = __expf(mrun - mnew);   // 0 on first tile (-inf - finite)

        float p0 = __expf(s0[0] - mnew), p1 = __expf(s0[1] - mnew);
        float p2 = __expf(s0[2] - mnew), p3 = __expf(s0[3] - mnew);
        float p4 = __expf(s1[0] - mnew), p5 = __expf(s1[1] - mnew);
        float p6 = __expf(s1[2] - mnew), p7 = __expf(s1[3] - mnew);
        float ps = ((p0 + p1) + (p2 + p3)) + ((p4 + p5) + (p6 + p7));
        ps += __shfl_xor(ps, 16, 64);
        ps += __shfl_xor(ps, 32, 64);
        lrun = lrun * corr + ps;
        mrun = mnew;
#pragma unroll
        for (int t = 0; t < 4; ++t) { acc0[t] *= corr; acc1[t] *= corr; }

        // pack P to bf16 pairs: pk{c}{v}: c = m-half (0:[m0..+15],1:[+16..+31])
        unsigned int pk00 = packbf(p0, p1), pk01 = packbf(p2, p3);
        unsigned int pk10 = packbf(p4, p5), pk11 = packbf(p6, p7);
        // redistribute to PV B-operand: lane (h,q) needs m' = 8h+r, r=0..7
        unsigned int a0 = __shfl(pk00, src0, 64), b0 = __shfl(pk10, src0, 64);
        unsigned int a1 = __shfl(pk01, src0, 64), b1 = __shfl(pk11, src0, 64);
        unsigned int a2 = __shfl(pk00, src1, 64), b2 = __shfl(pk10, src1, 64);
        unsigned int a3 = __shfl(pk01, src1, 64), b3 = __shfl(pk11, src1, 64);
        u32x4 Bu = { (h < 2) ? a0 : b0, (h < 2) ? a1 : b1,
                     (h < 2) ? a2 : b2, (h < 2) ? a3 : b3 };
        bf16x8 pfrag = __builtin_bit_cast(bf16x8, Bu);

        // V fragments (A-operand): A[i][m] = g[i][m0+m]; lane: i=q(+16), m=8h+j
        bf16x8 v0 = *(const bf16x8*)(vb + (size_t)q * BN + m0 + 8 * h);
        bf16x8 v1 = *(const bf16x8*)(vb + (size_t)(16 + q) * BN + m0 + 8 * h);
        acc0 = __builtin_amdgcn_mfma_f32_16x16x32_bf16(v0, pfrag, acc0, 0, 0, 0);
        acc1 = __builtin_amdgcn_mfma_f32_16x16x32_bf16(v1, pfrag, acc1, 0, 0, 0);
    }

    float inv = 1.0f / lrun;
    float* yb = yT + (size_t)b * DI * BN;
#pragma unroll
    for (int t = 0; t < 4; ++t) {
        yb[(size_t)(4 * h + t) * BN + n0 + q]      = acc0[t] * inv;
        yb[(size_t)(16 + 4 * h + t) * BN + n0 + q] = acc1[t] * inv;
    }
}

// ---------------------------------------------------------------------------
// Kernel 3: out[b][o][n] = sum_i W_w[o][i] * yT[b][i][n] + W_b[o] + x[b][o][n]
// ---------------------------------------------------------------------------
__global__ __launch_bounds__(256) void outconv_kernel(
    const float* __restrict__ yT, const float* __restrict__ Ww,
    const float* __restrict__ Wb, const float* __restrict__ x,
    float* __restrict__ out)
{
    __shared__ float wsh[32 * DI];
    __shared__ float bsh[32];
    const int b = blockIdx.z;
    const int oc0 = blockIdx.y * 32;
    const int tid = threadIdx.x;
    for (int i = tid; i < 32 * DI; i += 256)
        wsh[i] = Ww[(size_t)(oc0 + i / DI) * DI + (i % DI)];
    if (tid < 32) bsh[tid] = Wb[oc0 + tid];
    __syncthreads();

    const int n = blockIdx.x * 256 + tid;
    const float* yp = yT + (size_t)b * DI * BN + n;
    float acc[32];
#pragma unroll
    for (int o = 0; o < 32; ++o) acc[o] = bsh[o];
    for (int i = 0; i < DI; ++i) {
        float yv = yp[(size_t)i * BN];
#pragma unroll
        for (int o = 0; o < 32; ++o) acc[o] += wsh[o * DI + i] * yv;
    }
    const float* xp = x + ((size_t)b * CIN + oc0) * BN + n;
    float* op = out + ((size_t)b * CIN + oc0) * BN + n;
#pragma unroll
    for (int o = 0; o < 32; ++o) op[(size_t)o * BN] = acc[o] + xp[(size_t)o * BN];
}

// ---------------------------------------------------------------------------
extern "C" void kernel_launch(void* const* d_in, const int* in_sizes, int n_in,
                              void* d_out, int out_size, void* d_ws, size_t ws_size,
                              hipStream_t stream)
{
    const float* x    = (const float*)d_in[0];
    const float* g_w  = (const float*)d_in[1];
    const float* g_b  = (const float*)d_in[2];
    const float* th_w = (const float*)d_in[3];
    const float* th_b = (const float*)d_in[4];
    const float* ph_w = (const float*)d_in[5];
    const float* ph_b = (const float*)d_in[6];
    const float* W_w  = (const float*)d_in[7];
    const float* W_b  = (const float*)d_in[8];
    float* out = (float*)d_out;

    char* ws = (char*)d_ws;
    unsigned short* qT = (unsigned short*)(ws);                 // 1179648 B
    unsigned short* kT = (unsigned short*)(ws + 1179648);       // 1179648 B
    unsigned short* vv = (unsigned short*)(ws + 2359296);       // 1179648 B
    float*          yT = (float*)        (ws + 3538944);        // 2359296 B

    dim3 g1(BN / 256, 3, NB);
    qkv_kernel<<<g1, 256, 0, stream>>>(x, g_w, g_b, th_w, th_b, ph_w, ph_b,
                                       qT, kT, vv);
    dim3 g2(BN / 16, NB);
    attn_kernel<<<g2, 64, 0, stream>>>(qT, kT, vv, yT);
    dim3 g3(BN / 256, 2, NB);
    outconv_kernel<<<g3, 256, 0, stream>>>(yT, W_w, W_b, x, out);
}

// Round 4
// 228.013 us; speedup vs baseline: 1.2616x; 1.2616x over previous
//
#include <hip/hip_runtime.h>
#include <cstdint>

#define BN 9216      // N = H*W = 96*96
#define NB 2         // batch
#define CIN 64       // C
#define DI 32        // inter
#define LOG2E 1.4426950408889634f

typedef __attribute__((ext_vector_type(4))) float f32x4;
typedef __attribute__((ext_vector_type(8))) __bf16 bf16x8;
typedef __attribute__((ext_vector_type(4))) __bf16 bf16x4;
typedef __attribute__((ext_vector_type(4))) short s16x4;
typedef __attribute__((ext_vector_type(4))) unsigned int u32x4;

// fp32 -> bf16 bits, round-to-nearest-even (manual, proven path for qkv)
__device__ __forceinline__ unsigned short f2bf(float f) {
    unsigned int u = __builtin_bit_cast(unsigned int, f);
    u += 0x7FFFu + ((u >> 16) & 1u);
    return (unsigned short)(u >> 16);
}
__device__ __forceinline__ unsigned int packbf(float lo, float hi) {
    return (unsigned int)f2bf(lo) | ((unsigned int)f2bf(hi) << 16);
}

// hardware exp2 (v_exp_f32 IS 2^x); exp2(-inf)=0 handles first-tile corr
__device__ __forceinline__ float exp2_hw(float x) {
    float r;
    asm("v_exp_f32 %0, %1" : "=v"(r) : "v"(x));
    return r;
}

// 16x16x16 bf16 MFMA: A[i][k] lane i=lane&15, k=4*(lane>>4)+j; B same-k,
// n=lane&15; C/D col=lane&15, row=4*(lane>>4)+reg (same family as verified
// 16x16x32 mapping, k-groups of 4 instead of 8).
__device__ __forceinline__ f32x4 mfma16(bf16x4 a, bf16x4 b, f32x4 c) {
#if __has_builtin(__builtin_amdgcn_mfma_f32_16x16x16bf16_1k)
    return __builtin_amdgcn_mfma_f32_16x16x16bf16_1k(
        __builtin_bit_cast(s16x4, a), __builtin_bit_cast(s16x4, b), c, 0, 0, 0);
#elif __has_builtin(__builtin_amdgcn_mfma_f32_16x16x16_bf16)
    return __builtin_amdgcn_mfma_f32_16x16x16_bf16(a, b, c, 0, 0, 0);
#else
    f32x4 d;
    asm("v_mfma_f32_16x16x16_bf16 %0, %1, %2, %3"
        : "=v"(d) : "v"(a), "v"(b), "v"(c));
    return d;
#endif
}

// ---------------------------------------------------------------------------
// Kernel 1: fused conv1x1 for phi (Q), theta (K), g (V).
//   qT: [B][N][32] bf16  (phi scaled by LOG2E -> scores in log2 domain)
//   kT: [B][N][32] bf16
//   v : [B][32][N] bf16
// ---------------------------------------------------------------------------
__global__ __launch_bounds__(128) void qkv_kernel(
    const float* __restrict__ x,
    const float* __restrict__ g_w, const float* __restrict__ g_b,
    const float* __restrict__ th_w, const float* __restrict__ th_b,
    const float* __restrict__ ph_w, const float* __restrict__ ph_b,
    unsigned short* __restrict__ qT, unsigned short* __restrict__ kT,
    unsigned short* __restrict__ vv)
{
    __shared__ float wsh[DI * CIN];
    __shared__ float bsh[DI];
    const int which = blockIdx.y;  // 0 = phi->qT, 1 = theta->kT, 2 = g->v
    const int b = blockIdx.z;
    const int tid = threadIdx.x;
    const float* w    = (which == 0) ? ph_w : (which == 1) ? th_w : g_w;
    const float* bias = (which == 0) ? ph_b : (which == 1) ? th_b : g_b;
    const float scale = (which == 0) ? LOG2E : 1.0f;   // fold log2e into Q
    for (int i = tid; i < DI * CIN; i += 128) wsh[i] = w[i] * scale;
    if (tid < DI) bsh[tid] = bias[tid] * scale;
    __syncthreads();

    const int n = blockIdx.x * 128 + tid;
    const float* xp = x + (size_t)b * CIN * BN + n;

    float acc[DI];
#pragma unroll
    for (int o = 0; o < DI; ++o) acc[o] = bsh[o];
    for (int c0 = 0; c0 < CIN; c0 += 8) {       // 8-wide load batches for ILP
        float xv[8];
#pragma unroll
        for (int u = 0; u < 8; ++u) xv[u] = xp[(size_t)(c0 + u) * BN];
#pragma unroll
        for (int u = 0; u < 8; ++u)
#pragma unroll
            for (int o = 0; o < DI; ++o) acc[o] += wsh[o * CIN + c0 + u] * xv[u];
    }

    if (which == 2) {
        unsigned short* vp = vv + (size_t)b * DI * BN + n;
#pragma unroll
        for (int o = 0; o < DI; ++o) vp[(size_t)o * BN] = f2bf(acc[o]);
    } else {
        unsigned short* outp = ((which == 0) ? qT : kT) + ((size_t)b * BN + n) * DI;
        unsigned int pk[16];
#pragma unroll
        for (int j = 0; j < 16; ++j) pk[j] = packbf(acc[2 * j], acc[2 * j + 1]);
        u32x4* o4 = (u32x4*)outp;
#pragma unroll
        for (int j = 0; j < 4; ++j) {
            u32x4 t = {pk[4 * j], pk[4 * j + 1], pk[4 * j + 2], pk[4 * j + 3]};
            o4[j] = t;
        }
    }
}

// ---------------------------------------------------------------------------
// Kernel 2: flash attention. Block = 512 threads = 8 waves.
// Each wave: 2 n-tiles (32 queries), 8-way m-split (m0 = w*32 step 256).
// Swapped QK^T (mfma_16x16x32): lane holds S[m0+4h+t][q] -> feeds PV's
// mfma_16x16x16 B-operand (k=4h+j) directly, zero cross-lane repack.
// Online softmax in log2 domain, deferred-max THR=8.
// LDS combine of 8 partial (m,l,acc) per tile.
// ---------------------------------------------------------------------------
__global__ __launch_bounds__(512) void attn_kernel(
    const unsigned short* __restrict__ qT, const unsigned short* __restrict__ kT,
    const unsigned short* __restrict__ vv, float* __restrict__ yT)
{
    __shared__ float red_m[8][2][16];
    __shared__ float red_l[8][2][16];
    __shared__ float red_acc[8][2][512];   // [wave][tile][i*16+q]

    const int b = blockIdx.y;
    const int n0 = blockIdx.x * 32;        // 32 queries per block
    const int tid = threadIdx.x;
    const int w = tid >> 6;
    const int lane = tid & 63;
    const int h = lane >> 4;
    const int q = lane & 15;

    const unsigned short* qTb = qT + (size_t)b * BN * DI;
    const unsigned short* kTb = kT + (size_t)b * BN * DI;
    const unsigned short* vb  = vv + (size_t)b * DI * BN;

    bf16x8 qfA = *(const bf16x8*)(qTb + ((size_t)(n0 + q)) * DI + 8 * h);
    bf16x8 qfB = *(const bf16x8*)(qTb + ((size_t)(n0 + 16 + q)) * DI + 8 * h);
    const f32x4 zero = {0.f, 0.f, 0.f, 0.f};
    f32x4 a0A = zero, a1A = zero, a0B = zero, a1B = zero;
    float mA = -INFINITY, lA = 0.f;
    float mB = -INFINITY, lB = 0.f;

    const unsigned short* vrow0 = vb + (size_t)q * BN;
    const unsigned short* vrow1 = vb + (size_t)(16 + q) * BN;

    for (int m0 = w * 32; m0 < BN; m0 += 256) {
        bf16x8 k0 = *(const bf16x8*)(kTb + ((size_t)(m0 + q)) * DI + 8 * h);
        bf16x8 k1 = *(const bf16x8*)(kTb + ((size_t)(m0 + 16 + q)) * DI + 8 * h);
        f32x4 s0A = __builtin_amdgcn_mfma_f32_16x16x32_bf16(k0, qfA, zero, 0, 0, 0);
        f32x4 s1A = __builtin_amdgcn_mfma_f32_16x16x32_bf16(k1, qfA, zero, 0, 0, 0);
        f32x4 s0B = __builtin_amdgcn_mfma_f32_16x16x32_bf16(k0, qfB, zero, 0, 0, 0);
        f32x4 s1B = __builtin_amdgcn_mfma_f32_16x16x32_bf16(k1, qfB, zero, 0, 0, 0);

        bf16x4 v00 = *(const bf16x4*)(vrow0 + m0 + 4 * h);
        bf16x4 v01 = *(const bf16x4*)(vrow0 + m0 + 16 + 4 * h);
        bf16x4 v10 = *(const bf16x4*)(vrow1 + m0 + 4 * h);
        bf16x4 v11 = *(const bf16x4*)(vrow1 + m0 + 16 + 4 * h);

        // ---- tile A ----
        {
            float tmax = fmaxf(fmaxf(fmaxf(s0A[0], s0A[1]), fmaxf(s0A[2], s0A[3])),
                               fmaxf(fmaxf(s1A[0], s1A[1]), fmaxf(s1A[2], s1A[3])));
            tmax = fmaxf(tmax, __shfl_xor(tmax, 16, 64));
            tmax = fmaxf(tmax, __shfl_xor(tmax, 32, 64));
            if (__any(tmax > mA + 8.0f)) {            // deferred-max rescale
                float mnew = fmaxf(mA, tmax);
                float corr = exp2_hw(mA - mnew);
                lA *= corr;
#pragma unroll
                for (int t = 0; t < 4; ++t) { a0A[t] *= corr; a1A[t] *= corr; }
                mA = mnew;
            }
            float p0 = exp2_hw(s0A[0] - mA), p1 = exp2_hw(s0A[1] - mA);
            float p2 = exp2_hw(s0A[2] - mA), p3 = exp2_hw(s0A[3] - mA);
            float p4 = exp2_hw(s1A[0] - mA), p5 = exp2_hw(s1A[1] - mA);
            float p6 = exp2_hw(s1A[2] - mA), p7 = exp2_hw(s1A[3] - mA);
            lA += ((p0 + p1) + (p2 + p3)) + ((p4 + p5) + (p6 + p7)); // per-lane partial
            bf16x4 pf0 = {(__bf16)p0, (__bf16)p1, (__bf16)p2, (__bf16)p3};
            bf16x4 pf1 = {(__bf16)p4, (__bf16)p5, (__bf16)p6, (__bf16)p7};
            a0A = mfma16(v00, pf0, a0A);
            a0A = mfma16(v01, pf1, a0A);
            a1A = mfma16(v10, pf0, a1A);
            a1A = mfma16(v11, pf1, a1A);
        }
        // ---- tile B ----
        {
            float tmax = fmaxf(fmaxf(fmaxf(s0B[0], s0B[1]), fmaxf(s0B[2], s0B[3])),
                               fmaxf(fmaxf(s1B[0], s1B[1]), fmaxf(s1B[2], s1B[3])));
            tmax = fmaxf(tmax, __shfl_xor(tmax, 16, 64));
            tmax = fmaxf(tmax, __shfl_xor(tmax, 32, 64));
            if (__any(tmax > mB + 8.0f)) {
                float mnew = fmaxf(mB, tmax);
                float corr = exp2_hw(mB - mnew);
                lB *= corr;
#pragma unroll
                for (int t = 0; t < 4; ++t) { a0B[t] *= corr; a1B[t] *= corr; }
                mB = mnew;
            }
            float p0 = exp2_hw(s0B[0] - mB), p1 = exp2_hw(s0B[1] - mB);
            float p2 = exp2_hw(s0B[2] - mB), p3 = exp2_hw(s0B[3] - mB);
            float p4 = exp2_hw(s1B[0] - mB), p5 = exp2_hw(s1B[1] - mB);
            float p6 = exp2_hw(s1B[2] - mB), p7 = exp2_hw(s1B[3] - mB);
            lB += ((p0 + p1) + (p2 + p3)) + ((p4 + p5) + (p6 + p7));
            bf16x4 pf0 = {(__bf16)p0, (__bf16)p1, (__bf16)p2, (__bf16)p3};
            bf16x4 pf1 = {(__bf16)p4, (__bf16)p5, (__bf16)p6, (__bf16)p7};
            a0B = mfma16(v00, pf0, a0B);
            a0B = mfma16(v01, pf1, a0B);
            a1B = mfma16(v10, pf0, a1B);
            a1B = mfma16(v11, pf1, a1B);
        }
    }

    // reduce per-lane partial l across h-groups (same q)
    lA += __shfl_xor(lA, 16, 64); lA += __shfl_xor(lA, 32, 64);
    lB += __shfl_xor(lB, 16, 64); lB += __shfl_xor(lB, 32, 64);

    if (lane < 16) {
        red_m[w][0][lane] = mA; red_l[w][0][lane] = lA;
        red_m[w][1][lane] = mB; red_l[w][1][lane] = lB;
    }
    __syncthreads();

    // each wave rescales its partial acc to the global max and parks in LDS
    {
        float MA = red_m[0][0][q], MB = red_m[0][1][q];
#pragma unroll
        for (int w2 = 1; w2 < 8; ++w2) {
            MA = fmaxf(MA, red_m[w2][0][q]);
            MB = fmaxf(MB, red_m[w2][1][q]);
        }
        float scA = exp2_hw(mA - MA), scB = exp2_hw(mB - MB);
#pragma unroll
        for (int t = 0; t < 4; ++t) {
            red_acc[w][0][(4 * h + t) * 16 + q]        = a0A[t] * scA;
            red_acc[w][0][(16 + 4 * h + t) * 16 + q]   = a1A[t] * scA;
            red_acc[w][1][(4 * h + t) * 16 + q]        = a0B[t] * scB;
            red_acc[w][1][(16 + 4 * h + t) * 16 + q]   = a1B[t] * scB;
        }
    }
    __syncthreads();

    // final: thread tid owns element (i = tid>>4, q2 = tid&15) of each tile
    {
        const int i = tid >> 4, q2 = tid & 15;
        float* yb = yT + (size_t)b * DI * BN + (size_t)i * BN + n0;
#pragma unroll
        for (int tt = 0; tt < 2; ++tt) {
            float M = red_m[0][tt][q2];
#pragma unroll
            for (int w2 = 1; w2 < 8; ++w2) M = fmaxf(M, red_m[w2][tt][q2]);
            float L = 0.f, y = 0.f;
#pragma unroll
            for (int w2 = 0; w2 < 8; ++w2) {
                L += exp2_hw(red_m[w2][tt][q2] - M) * red_l[w2][tt][q2];
                y += red_acc[w2][tt][tid];
            }
            yb[tt * 16 + q2] = y / L;
        }
    }
}

// ---------------------------------------------------------------------------
// Kernel 3: out[b][o][n] = sum_i W_w[o][i] * yT[b][i][n] + W_b[o] + x[b][o][n]
// ---------------------------------------------------------------------------
__global__ __launch_bounds__(128) void outconv_kernel(
    const float* __restrict__ yT, const float* __restrict__ Ww,
    const float* __restrict__ Wb, const float* __restrict__ x,
    float* __restrict__ out)
{
    __shared__ float wsh[32 * DI];
    __shared__ float bsh[32];
    const int b = blockIdx.z;
    const int oc0 = blockIdx.y * 32;
    const int tid = threadIdx.x;
    for (int i = tid; i < 32 * DI; i += 128)
        wsh[i] = Ww[(size_t)(oc0 + i / DI) * DI + (i % DI)];
    if (tid < 32) bsh[tid] = Wb[oc0 + tid];
    __syncthreads();

    const int n = blockIdx.x * 128 + tid;
    const float* yp = yT + (size_t)b * DI * BN + n;
    float acc[32];
#pragma unroll
    for (int o = 0; o < 32; ++o) acc[o] = bsh[o];
    for (int i0 = 0; i0 < DI; i0 += 8) {
        float yv[8];
#pragma unroll
        for (int u = 0; u < 8; ++u) yv[u] = yp[(size_t)(i0 + u) * BN];
#pragma unroll
        for (int u = 0; u < 8; ++u)
#pragma unroll
            for (int o = 0; o < 32; ++o) acc[o] += wsh[o * DI + i0 + u] * yv[u];
    }
    const float* xp = x + ((size_t)b * CIN + oc0) * BN + n;
    float* op = out + ((size_t)b * CIN + oc0) * BN + n;
#pragma unroll
    for (int o = 0; o < 32; ++o) op[(size_t)o * BN] = acc[o] + xp[(size_t)o * BN];
}

// ---------------------------------------------------------------------------
extern "C" void kernel_launch(void* const* d_in, const int* in_sizes, int n_in,
                              void* d_out, int out_size, void* d_ws, size_t ws_size,
                              hipStream_t stream)
{
    const float* x    = (const float*)d_in[0];
    const float* g_w  = (const float*)d_in[1];
    const float* g_b  = (const float*)d_in[2];
    const float* th_w = (const float*)d_in[3];
    const float* th_b = (const float*)d_in[4];
    const float* ph_w = (const float*)d_in[5];
    const float* ph_b = (const float*)d_in[6];
    const float* W_w  = (const float*)d_in[7];
    const float* W_b  = (const float*)d_in[8];
    float* out = (float*)d_out;

    char* ws = (char*)d_ws;
    unsigned short* qT = (unsigned short*)(ws);                 // 1179648 B
    unsigned short* kT = (unsigned short*)(ws + 1179648);       // 1179648 B
    unsigned short* vv = (unsigned short*)(ws + 2359296);       // 1179648 B
    float*          yT = (float*)        (ws + 3538944);        // 2359296 B

    dim3 g1(BN / 128, 3, NB);
    qkv_kernel<<<g1, 128, 0, stream>>>(x, g_w, g_b, th_w, th_b, ph_w, ph_b,
                                       qT, kT, vv);
    dim3 g2(BN / 32, NB);
    attn_kernel<<<g2, 512, 0, stream>>>(qT, kT, vv, yT);
    dim3 g3(BN / 128, 2, NB);
    outconv_kernel<<<g3, 128, 0, stream>>>(yT, W_w, W_b, x, out);
}